// Round 6
// baseline (408.648 us; speedup 1.0000x reference)
//
#include <hip/hip_runtime.h>
#include <hip/hip_bf16.h>

#define NN 524288     // nodes
#define NE 2097152    // edges
#define NS 8192       // subgraphs
#define NG 64         // groups
#define FIN 64
#define HIDDEN 128

#define NB 512        // coarse bins (dst >> 10)
#define BIN_NODES 1024
#define CAP 4608      // bin capacity: mean 4096 + 8 sigma

typedef __attribute__((ext_vector_type(8))) unsigned short ushort8;
typedef __attribute__((ext_vector_type(8))) short bf16x8;
typedef __attribute__((ext_vector_type(4))) float floatx4;

__device__ __forceinline__ unsigned short f2b(float f) {
  union { float f; unsigned int u; } c; c.f = f;
  unsigned int u = c.u;
  unsigned int r = (u + 0x7FFFu + ((u >> 16) & 1u)) >> 16;  // RNE
  return (unsigned short)r;
}
__device__ __forceinline__ float b2f(unsigned short b) {
  union { unsigned int u; float f; } c; c.u = ((unsigned int)b) << 16;
  return c.f;
}

// ---------------------------------------------------------------------------
// K0: cast x -> bf16 (xb), 8 floats/thread, blocks [0,16384).
//     prepw fused as blocks [16384,16448): Wt[n][k] = bf16(Wl|Wr transposed).
// ---------------------------------------------------------------------------
__global__ __launch_bounds__(256) void k_cast(const float* __restrict__ x,
                                              unsigned short* __restrict__ xb,
                                              const float* __restrict__ Wl,
                                              const float* __restrict__ Wr,
                                              unsigned short* __restrict__ Wt) {
  int bid = blockIdx.x;
  if (bid < 16384) {
    size_t i = ((size_t)bid * 256 + threadIdx.x) * 8;
    float4 v0 = *(const float4*)(x + i);
    float4 v1 = *(const float4*)(x + i + 4);
    ushort8 r;
    r[0] = f2b(v0.x); r[1] = f2b(v0.y); r[2] = f2b(v0.z); r[3] = f2b(v0.w);
    r[4] = f2b(v1.x); r[5] = f2b(v1.y); r[6] = f2b(v1.z); r[7] = f2b(v1.w);
    *(ushort8*)(xb + i) = r;
  } else {
    int i = (bid - 16384) * 256 + threadIdx.x;  // 64 blocks -> 16384
    int n = i >> 7, k = i & 127;
    float v = (k < FIN) ? Wl[k * HIDDEN + n] : Wr[(k - FIN) * HIDDEN + n];
    Wt[n * HIDDEN + k] = f2b(v);
  }
}

// ---------------------------------------------------------------------------
// K1a v2: coarse binning with LDS counting-sort so the global write-out is
// COALESCED (sorted array -> consecutive lanes hit consecutive addresses,
// mean run per (block,bin) = 8 words).
// pack = (dst_local << 19) | src   (src < 2^19, dst_local < 2^10)
// ---------------------------------------------------------------------------
__global__ __launch_bounds__(256) void k_bin1(const int* __restrict__ ei,
                                              int* __restrict__ binCursor,
                                              unsigned int* __restrict__ pairs) {
  __shared__ unsigned int pk[4096];        // input packed
  __shared__ unsigned int pks[4096];       // bin-sorted packed
  __shared__ unsigned short bn[4096];      // bin of input elem
  __shared__ unsigned short bns[4096];     // bin of sorted elem
  __shared__ int cnt[NB];                  // hist -> scatter cursor
  __shared__ int ofs_s[NB];                // local start of bin in sorted array
  __shared__ int base[NB];                 // global base within bin region
  __shared__ int ps[256];
  const int t = threadIdx.x;
  const int eBase = blockIdx.x * 4096;
  cnt[t] = 0; cnt[t + 256] = 0;
  __syncthreads();
#pragma unroll
  for (int i = 0; i < 16; ++i) {
    int j = i * 256 + t;
    int e = eBase + j;
    int src = ei[e];
    int dst = ei[NE + e];
    int bin = dst >> 10;
    pk[j] = ((unsigned int)(dst & 1023) << 19) | (unsigned int)src;
    bn[j] = (unsigned short)bin;
    atomicAdd(&cnt[bin], 1);
  }
  __syncthreads();
  // scan over 512 bins (thread t owns bins 2t, 2t+1) + global reservation
  int c0 = cnt[2 * t], c1 = cnt[2 * t + 1];
  int tot = c0 + c1;
  ps[t] = tot;
  __syncthreads();
  for (int off = 1; off < 256; off <<= 1) {
    int v = 0;
    if (t >= off) v = ps[t - off];
    __syncthreads();
    ps[t] += v;
    __syncthreads();
  }
  {
    int e0 = ps[t] - tot;
    int e1 = e0 + c0;
    ofs_s[2 * t] = e0; ofs_s[2 * t + 1] = e1;
    cnt[2 * t] = e0; cnt[2 * t + 1] = e1;     // scatter cursors
    base[2 * t]     = atomicAdd(&binCursor[2 * t], c0);
    base[2 * t + 1] = atomicAdd(&binCursor[2 * t + 1], c1);
  }
  __syncthreads();
  // LDS scatter into sorted order
#pragma unroll
  for (int i = 0; i < 16; ++i) {
    int j = i * 256 + t;
    int bin = bn[j];
    int p = atomicAdd(&cnt[bin], 1);
    pks[p] = pk[j];
    bns[p] = (unsigned short)bin;
  }
  __syncthreads();
  // coalesced write-out: consecutive i -> consecutive global addr within runs
#pragma unroll
  for (int i = 0; i < 16; ++i) {
    int j = i * 256 + t;
    int bin = bns[j];
    pairs[(size_t)bin * CAP + base[bin] + (j - ofs_s[bin])] = pks[j];
  }
}

// ---------------------------------------------------------------------------
// K1b: per-bin local CSR.  One block per bin: stage pairs to LDS, LDS hist of
// 1024 local nodes, LDS scan -> start offsets S[n + (n>>10)] (+sentinel),
// then place src in-place over the bin's pairs region via LDS cursors.
// ---------------------------------------------------------------------------
__global__ __launch_bounds__(256) void k_bin2(const int* __restrict__ binCursor,
                                              unsigned int* __restrict__ pairs,
                                              int* __restrict__ S) {
  __shared__ unsigned int pk[CAP];
  __shared__ int cnt[BIN_NODES];
  __shared__ int ps[256];
  const int t = threadIdx.x;
  const int b = blockIdx.x;
  int total = binCursor[b];
  if (total > CAP) total = CAP;   // statistical impossibility; guard LDS
  const int gbase = b * CAP;

  for (int i = t; i < total; i += 256) pk[i] = pairs[gbase + i];
  cnt[t] = 0; cnt[t + 256] = 0; cnt[t + 512] = 0; cnt[t + 768] = 0;
  __syncthreads();

  for (int i = t; i < total; i += 256) atomicAdd(&cnt[pk[i] >> 19], 1);
  __syncthreads();

  // scan: thread t owns local nodes 4t..4t+3
  int c0 = cnt[4 * t], c1 = cnt[4 * t + 1], c2 = cnt[4 * t + 2], c3 = cnt[4 * t + 3];
  int tot4 = c0 + c1 + c2 + c3;
  ps[t] = tot4;
  __syncthreads();
  for (int off = 1; off < 256; off <<= 1) {
    int v = 0;
    if (t >= off) v = ps[t - off];
    __syncthreads();
    ps[t] += v;
    __syncthreads();
  }
  int e0 = ps[t] - tot4;
  int e1 = e0 + c0, e2 = e1 + c1, e3 = e2 + c2;
  cnt[4 * t] = e0; cnt[4 * t + 1] = e1; cnt[4 * t + 2] = e2; cnt[4 * t + 3] = e3;
  int sidx = b * (BIN_NODES + 1) + 4 * t;
  S[sidx]     = gbase + e0;
  S[sidx + 1] = gbase + e1;
  S[sidx + 2] = gbase + e2;
  S[sidx + 3] = gbase + e3;
  if (t == 0) S[b * (BIN_NODES + 1) + BIN_NODES] = gbase + total;
  __syncthreads();

  for (int i = t; i < total; i += 256) {
    unsigned int p = pk[i];
    int dl = p >> 19;
    int ofs = atomicAdd(&cnt[dl], 1);
    pairs[gbase + ofs] = p & 0x7FFFFu;   // now holds src only
  }
}

// ---------------------------------------------------------------------------
// K2 v7 (fused aggregate+conv+pool).  Gather = v5 verbatim (known 80.7us,
// bit-identical summation tree) PLUS:
//  (a) degree-sorted node->lane-group mapping (LDS counting sort, stable
//      within degree): a wave's 16 nodes have similar degree, cutting the
//      exec-masked overhang (wave runs max-deg of its nodes; E[max of 16
//      Poisson(4)] ~ 9 vs sorted ~mean) -- processing order is free, output
//      written to As[nl] stays in place;
//  (b) row pointers rp_s[129] cached in LDS (contiguous incl. sentinel).
// MFMA phase unchanged (wave-per-column-slice, B operand in VGPRs from Wt).
// ---------------------------------------------------------------------------
#define CB_NODES 128
__global__ __launch_bounds__(512, 6) void k_aggconv(const unsigned short* __restrict__ xb,
                                                    const int* __restrict__ S,
                                                    const unsigned int* __restrict__ bucket,
                                                    const int* __restrict__ node_batch,
                                                    const unsigned short* __restrict__ Wt,
                                                    const float* __restrict__ bconv,
                                                    float* __restrict__ g) {
  __shared__ unsigned short As[128 * 136];  // [m][0:64)=agg, [64:128)=x; later h[m][n]
  __shared__ int nb_s[CB_NODES];
  __shared__ int rp_s[CB_NODES + 1];
  __shared__ unsigned char ord[CB_NODES];
  __shared__ int dcnt[33];
  const int t = threadIdx.x;
  const int n0 = blockIdx.x * CB_NODES;
  const int sidx0 = n0 + (n0 >> 10);

  if (t < CB_NODES) nb_s[t] = node_batch[n0 + t];
  if (t < CB_NODES + 1) rp_s[t] = S[sidx0 + t];   // valid incl. sentinel at bin end
  if (t >= 512 - 33) dcnt[t - (512 - 33)] = 0;

  // stage x half of As.  1024 ushort8 slots, 2/thread.
#pragma unroll
  for (int it = 0; it < 2; ++it) {
    int i = it * 512 + t;
    int n = i >> 3;
    int c = i & 7;
    *(ushort8*)(As + n * 136 + 64 + c * 8) =
        *(const ushort8*)(xb + (size_t)(n0 + n) * FIN + c * 8);
  }
  __syncthreads();   // rp_s, dcnt ready

  // degree counting-sort -> ord[]
  if (t < CB_NODES) {
    int d = rp_s[t + 1] - rp_s[t];
    if (d > 32) d = 32;
    atomicAdd(&dcnt[d], 1);
  }
  __syncthreads();
  if (t == 0) {
    int run = 0;
    for (int d = 0; d <= 32; ++d) { int c = dcnt[d]; dcnt[d] = run; run += c; }
  }
  __syncthreads();
  if (t < CB_NODES) {
    int d = rp_s[t + 1] - rp_s[t];
    if (d > 32) d = 32;
    int slot = atomicAdd(&dcnt[d], 1);
    ord[slot] = (unsigned char)t;
  }
  __syncthreads();   // ord ready

  // phase 2: gather (v5 body).  4 lanes per node (32B each), 128 nodes/pass.
  {
    const int lane4 = t & 3;          // 16-elem slice within row
    const int grp = t >> 2;           // 0..127: sorted position
    const int nl = ord[grp];          // actual node within block
    const int rp0 = rp_s[nl];
    const int rp1 = rp_s[nl + 1];
    const int co = lane4 << 4;        // element offset of this lane's 32B slice

    float a[16];
#pragma unroll
    for (int j = 0; j < 16; ++j) a[j] = 0.f;

    int e = rp0;
    for (; e + 3 < rp1; e += 4) {
      int s0 = bucket[e], s1 = bucket[e + 1], s2 = bucket[e + 2], s3 = bucket[e + 3];
      const unsigned short* r0 = xb + (size_t)s0 * FIN + co;
      const unsigned short* r1 = xb + (size_t)s1 * FIN + co;
      const unsigned short* r2 = xb + (size_t)s2 * FIN + co;
      const unsigned short* r3 = xb + (size_t)s3 * FIN + co;
      ushort8 v0a = *(const ushort8*)(r0), v0b = *(const ushort8*)(r0 + 8);
      ushort8 v1a = *(const ushort8*)(r1), v1b = *(const ushort8*)(r1 + 8);
      ushort8 v2a = *(const ushort8*)(r2), v2b = *(const ushort8*)(r2 + 8);
      ushort8 v3a = *(const ushort8*)(r3), v3b = *(const ushort8*)(r3 + 8);
#pragma unroll
      for (int j = 0; j < 8; ++j) {
        a[j]     += (b2f(v0a[j]) + b2f(v1a[j])) + (b2f(v2a[j]) + b2f(v3a[j]));
        a[8 + j] += (b2f(v0b[j]) + b2f(v1b[j])) + (b2f(v2b[j]) + b2f(v3b[j]));
      }
    }
    for (; e < rp1; ++e) {
      int s0 = bucket[e];
      const unsigned short* r0 = xb + (size_t)s0 * FIN + co;
      ushort8 v0a = *(const ushort8*)(r0), v0b = *(const ushort8*)(r0 + 8);
#pragma unroll
      for (int j = 0; j < 8; ++j) {
        a[j] += b2f(v0a[j]);
        a[8 + j] += b2f(v0b[j]);
      }
    }
    float rdeg = 1.f / fmaxf((float)(rp1 - rp0), 1.f);
    ushort8 r0, r1;
#pragma unroll
    for (int j = 0; j < 8; ++j) { r0[j] = f2b(a[j] * rdeg); r1[j] = f2b(a[8 + j] * rdeg); }
    *(ushort8*)(As + nl * 136 + co) = r0;
    *(ushort8*)(As + nl * 136 + co + 8) = r1;
  }

  // phase 3: MFMA.  wave w owns output cols w*16..w*16+15, all 128 rows.
  const int wave = t >> 6;
  const int lane = t & 63;
  const int l16 = lane & 15;
  const int quad = lane >> 4;

  bf16x8 bfrag[4];
#pragma unroll
  for (int ks = 0; ks < 4; ++ks)
    bfrag[ks] = *(const bf16x8*)(Wt + (size_t)(wave * 16 + l16) * HIDDEN + ks * 32 + quad * 8);
  float bv = bconv[wave * 16 + l16];

  floatx4 acc[8];
#pragma unroll
  for (int mt = 0; mt < 8; ++mt) acc[mt] = (floatx4){0.f, 0.f, 0.f, 0.f};

  __syncthreads();

#pragma unroll
  for (int mt = 0; mt < 8; ++mt) {
#pragma unroll
    for (int ks = 0; ks < 4; ++ks) {
      bf16x8 a = *(const bf16x8*)(As + (mt * 16 + l16) * 136 + ks * 32 + quad * 8);
      acc[mt] = __builtin_amdgcn_mfma_f32_16x16x32_bf16(a, bfrag[ks], acc[mt], 0, 0, 0);
    }
  }

  __syncthreads();   // all waves done reading As before h overwrites it

  // epilogue: bias+relu -> h bf16 into As
  {
    int col = wave * 16 + l16;
#pragma unroll
    for (int mt = 0; mt < 8; ++mt)
#pragma unroll
      for (int r = 0; r < 4; ++r) {
        int row = mt * 16 + quad * 4 + r;
        float hv = fmaxf(acc[mt][r] + bv, 0.f);
        As[row * 136 + col] = f2b(hv);
      }
  }
  __syncthreads();

  // segmented pool: 4 threads per col, 32 nodes each (sorted node_batch)
  {
    int j = t & 127;
    int q = t >> 7;
    int ns = q * 32, ne = ns + 32;
    float sum = 0.f;
    int cur = nb_s[ns];
    for (int n = ns; n < ne; ++n) {
      int b = nb_s[n];
      if (b != cur) {
        unsafeAtomicAdd(&g[(size_t)cur * HIDDEN + j], sum);
        sum = 0.f;
        cur = b;
      }
      sum += b2f(As[n * 136 + j]);
    }
    unsafeAtomicAdd(&g[(size_t)cur * HIDDEN + j], sum);
  }
}

// ---------------------------------------------------------------------------
// K3 v2: MLP head.  W1 staged in LDS once per block (64KB), 16 subgraphs per
// block (4 waves x 4) -> W1 L2 traffic 512MB -> 32MB.
// ---------------------------------------------------------------------------
#define HB_SG 16
__global__ __launch_bounds__(256) void k_head(const float* __restrict__ g,
                                              const float* __restrict__ W1,
                                              const float* __restrict__ b1,
                                              const float* __restrict__ W2,
                                              const float* __restrict__ b2,
                                              const float* __restrict__ wts,
                                              const int* __restrict__ sgb,
                                              float* __restrict__ egy,
                                              float* __restrict__ nrm) {
  __shared__ float W1s[HIDDEN * HIDDEN];  // 64KB
  const int t = threadIdx.x;
#pragma unroll
  for (int it = 0; it < 16; ++it) {
    int i = (it * 256 + t) * 4;
    *(float4*)(W1s + i) = *(const float4*)(W1 + i);
  }
  const int wv = t >> 6;
  const int lane = t & 63;
  const float b1a = b1[lane], b1b = b1[lane + 64];
  const float w2a = W2[lane], w2b = W2[lane + 64];
  __syncthreads();
#pragma unroll
  for (int q = 0; q < HB_SG / 4; ++q) {
    int s = blockIdx.x * HB_SG + q * 4 + wv;
    const float* grow = g + (size_t)s * HIDDEN;
    float acc0 = b1a, acc1 = b1b;
    for (int k = 0; k < HIDDEN; ++k) {
      float gk = grow[k];  // wave-uniform
      acc0 = fmaf(gk, W1s[k * HIDDEN + lane], acc0);
      acc1 = fmaf(gk, W1s[k * HIDDEN + 64 + lane], acc1);
    }
    float t0 = acc0 > 0.f ? acc0 : 0.01f * acc0;
    float t1 = acc1 > 0.f ? acc1 : 0.01f * acc1;
    float part = t0 * w2a + t1 * w2b;
#pragma unroll
    for (int off = 32; off > 0; off >>= 1) part += __shfl_down(part, off, 64);
    if (lane == 0) {
      float sval = part + b2[0];
      float w = wts[s];
      int grp = sgb[s];
      unsafeAtomicAdd(&egy[grp], sval * w);
      unsafeAtomicAdd(&nrm[grp], w);
    }
  }
}

__global__ void k_final(const float* __restrict__ egy,
                        const float* __restrict__ nrm,
                        float* __restrict__ out) {
  int t = threadIdx.x;
  out[t] = egy[t] / nrm[t];
}

// ---------------------------------------------------------------------------
extern "C" void kernel_launch(void* const* d_in, const int* in_sizes, int n_in,
                              void* d_out, int out_size, void* d_ws, size_t ws_size,
                              hipStream_t stream) {
  const float* x   = (const float*)d_in[0];
  const int*   ei  = (const int*)d_in[1];
  const int*   nb  = (const int*)d_in[2];
  const float* wts = (const float*)d_in[3];
  const int*   sgb = (const int*)d_in[4];
  const float* Wl  = (const float*)d_in[5];
  const float* Wr  = (const float*)d_in[6];
  const float* bcv = (const float*)d_in[7];
  const float* W1  = (const float*)d_in[8];
  const float* b1  = (const float*)d_in[9];
  const float* W2  = (const float*)d_in[10];
  const float* b2  = (const float*)d_in[11];
  float* out = (float*)d_out;

  // ws layout (4B units), zeroed region first:
  //   binCursor[512] | g[NS*128] | egy[64] | nrm[64]   <- memset 0
  //   S[512*1025] | pairs[512*4608] | xb[NN*64 bf16] | Wt[16384 bf16]
  int*   binCursor = (int*)d_ws;
  float* g         = (float*)(binCursor + NB);
  float* egy       = g + (size_t)NS * HIDDEN;
  float* nrm       = egy + NG;
  int*   S         = (int*)(nrm + NG);
  unsigned int* pairs = (unsigned int*)(S + NB * (BIN_NODES + 1));
  unsigned short* xb   = (unsigned short*)(pairs + (size_t)NB * CAP);
  unsigned short* Wt   = xb + (size_t)NN * FIN;

  size_t zero_bytes = ((size_t)NB + (size_t)NS * HIDDEN + 2 * NG) * 4;
  hipMemsetAsync(d_ws, 0, zero_bytes, stream);

  k_cast <<<16448, 256, 0, stream>>>(x, xb, Wl, Wr, Wt);
  k_bin1 <<<NE / 4096, 256, 0, stream>>>(ei, binCursor, pairs);
  k_bin2 <<<NB, 256, 0, stream>>>(binCursor, pairs, S);
  k_aggconv<<<NN / CB_NODES, 512, 0, stream>>>(xb, S, pairs, nb, Wt, bcv, g);
  k_head<<<NS / HB_SG, 256, 0, stream>>>(g, W1, b1, W2, b2, wts, sgb, egy, nrm);
  k_final<<<1, 64, 0, stream>>>(egy, nrm, out);
}

// Round 7
// 391.253 us; speedup vs baseline: 1.0445x; 1.0445x over previous
//
#include <hip/hip_runtime.h>
#include <hip/hip_bf16.h>

#define NN 524288     // nodes
#define NE 2097152    // edges
#define NS 8192       // subgraphs
#define NG 64         // groups
#define FIN 64
#define HIDDEN 128

#define NB 512        // coarse bins (dst >> 10)
#define BIN_NODES 1024
#define CAP 4608      // bin capacity: mean 4096 + 8 sigma

typedef __attribute__((ext_vector_type(8))) unsigned short ushort8;
typedef __attribute__((ext_vector_type(8))) short bf16x8;
typedef __attribute__((ext_vector_type(4))) float floatx4;

__device__ __forceinline__ unsigned short f2b(float f) {
  union { float f; unsigned int u; } c; c.f = f;
  unsigned int u = c.u;
  unsigned int r = (u + 0x7FFFu + ((u >> 16) & 1u)) >> 16;  // RNE
  return (unsigned short)r;
}
__device__ __forceinline__ float b2f(unsigned short b) {
  union { unsigned int u; float f; } c; c.u = ((unsigned int)b) << 16;
  return c.f;
}

// ---------------------------------------------------------------------------
// K0: cast x -> bf16 (xb), 8 floats/thread, blocks [0,16384).
//     prepw fused as blocks [16384,16448): Wt[n][k] = bf16(Wl|Wr transposed).
// ---------------------------------------------------------------------------
__global__ __launch_bounds__(256) void k_cast(const float* __restrict__ x,
                                              unsigned short* __restrict__ xb,
                                              const float* __restrict__ Wl,
                                              const float* __restrict__ Wr,
                                              unsigned short* __restrict__ Wt) {
  int bid = blockIdx.x;
  if (bid < 16384) {
    size_t i = ((size_t)bid * 256 + threadIdx.x) * 8;
    float4 v0 = *(const float4*)(x + i);
    float4 v1 = *(const float4*)(x + i + 4);
    ushort8 r;
    r[0] = f2b(v0.x); r[1] = f2b(v0.y); r[2] = f2b(v0.z); r[3] = f2b(v0.w);
    r[4] = f2b(v1.x); r[5] = f2b(v1.y); r[6] = f2b(v1.z); r[7] = f2b(v1.w);
    *(ushort8*)(xb + i) = r;
  } else {
    int i = (bid - 16384) * 256 + threadIdx.x;  // 64 blocks -> 16384
    int n = i >> 7, k = i & 127;
    float v = (k < FIN) ? Wl[k * HIDDEN + n] : Wr[(k - FIN) * HIDDEN + n];
    Wt[n * HIDDEN + k] = f2b(v);
  }
}

// ---------------------------------------------------------------------------
// K1a v2: coarse binning with LDS counting-sort so the global write-out is
// COALESCED (sorted array -> consecutive lanes hit consecutive addresses,
// mean run per (block,bin) = 8 words).
// pack = (dst_local << 19) | src   (src < 2^19, dst_local < 2^10)
// ---------------------------------------------------------------------------
__global__ __launch_bounds__(256) void k_bin1(const int* __restrict__ ei,
                                              int* __restrict__ binCursor,
                                              unsigned int* __restrict__ pairs) {
  __shared__ unsigned int pk[4096];        // input packed
  __shared__ unsigned int pks[4096];       // bin-sorted packed
  __shared__ unsigned short bn[4096];      // bin of input elem
  __shared__ unsigned short bns[4096];     // bin of sorted elem
  __shared__ int cnt[NB];                  // hist -> scatter cursor
  __shared__ int ofs_s[NB];                // local start of bin in sorted array
  __shared__ int base[NB];                 // global base within bin region
  __shared__ int ps[256];
  const int t = threadIdx.x;
  const int eBase = blockIdx.x * 4096;
  cnt[t] = 0; cnt[t + 256] = 0;
  __syncthreads();
#pragma unroll
  for (int i = 0; i < 16; ++i) {
    int j = i * 256 + t;
    int e = eBase + j;
    int src = ei[e];
    int dst = ei[NE + e];
    int bin = dst >> 10;
    pk[j] = ((unsigned int)(dst & 1023) << 19) | (unsigned int)src;
    bn[j] = (unsigned short)bin;
    atomicAdd(&cnt[bin], 1);
  }
  __syncthreads();
  // scan over 512 bins (thread t owns bins 2t, 2t+1) + global reservation
  int c0 = cnt[2 * t], c1 = cnt[2 * t + 1];
  int tot = c0 + c1;
  ps[t] = tot;
  __syncthreads();
  for (int off = 1; off < 256; off <<= 1) {
    int v = 0;
    if (t >= off) v = ps[t - off];
    __syncthreads();
    ps[t] += v;
    __syncthreads();
  }
  {
    int e0 = ps[t] - tot;
    int e1 = e0 + c0;
    ofs_s[2 * t] = e0; ofs_s[2 * t + 1] = e1;
    cnt[2 * t] = e0; cnt[2 * t + 1] = e1;     // scatter cursors
    base[2 * t]     = atomicAdd(&binCursor[2 * t], c0);
    base[2 * t + 1] = atomicAdd(&binCursor[2 * t + 1], c1);
  }
  __syncthreads();
  // LDS scatter into sorted order
#pragma unroll
  for (int i = 0; i < 16; ++i) {
    int j = i * 256 + t;
    int bin = bn[j];
    int p = atomicAdd(&cnt[bin], 1);
    pks[p] = pk[j];
    bns[p] = (unsigned short)bin;
  }
  __syncthreads();
  // coalesced write-out: consecutive i -> consecutive global addr within runs
#pragma unroll
  for (int i = 0; i < 16; ++i) {
    int j = i * 256 + t;
    int bin = bns[j];
    pairs[(size_t)bin * CAP + base[bin] + (j - ofs_s[bin])] = pks[j];
  }
}

// ---------------------------------------------------------------------------
// K1b: per-bin local CSR.  One block per bin: stage pairs to LDS, LDS hist of
// 1024 local nodes, LDS scan -> start offsets S[n + (n>>10)] (+sentinel),
// then place src in-place over the bin's pairs region via LDS cursors.
// ---------------------------------------------------------------------------
__global__ __launch_bounds__(256) void k_bin2(const int* __restrict__ binCursor,
                                              unsigned int* __restrict__ pairs,
                                              int* __restrict__ S) {
  __shared__ unsigned int pk[CAP];
  __shared__ int cnt[BIN_NODES];
  __shared__ int ps[256];
  const int t = threadIdx.x;
  const int b = blockIdx.x;
  int total = binCursor[b];
  if (total > CAP) total = CAP;   // statistical impossibility; guard LDS
  const int gbase = b * CAP;

  for (int i = t; i < total; i += 256) pk[i] = pairs[gbase + i];
  cnt[t] = 0; cnt[t + 256] = 0; cnt[t + 512] = 0; cnt[t + 768] = 0;
  __syncthreads();

  for (int i = t; i < total; i += 256) atomicAdd(&cnt[pk[i] >> 19], 1);
  __syncthreads();

  // scan: thread t owns local nodes 4t..4t+3
  int c0 = cnt[4 * t], c1 = cnt[4 * t + 1], c2 = cnt[4 * t + 2], c3 = cnt[4 * t + 3];
  int tot4 = c0 + c1 + c2 + c3;
  ps[t] = tot4;
  __syncthreads();
  for (int off = 1; off < 256; off <<= 1) {
    int v = 0;
    if (t >= off) v = ps[t - off];
    __syncthreads();
    ps[t] += v;
    __syncthreads();
  }
  int e0 = ps[t] - tot4;
  int e1 = e0 + c0, e2 = e1 + c1, e3 = e2 + c2;
  cnt[4 * t] = e0; cnt[4 * t + 1] = e1; cnt[4 * t + 2] = e2; cnt[4 * t + 3] = e3;
  int sidx = b * (BIN_NODES + 1) + 4 * t;
  S[sidx]     = gbase + e0;
  S[sidx + 1] = gbase + e1;
  S[sidx + 2] = gbase + e2;
  S[sidx + 3] = gbase + e3;
  if (t == 0) S[b * (BIN_NODES + 1) + BIN_NODES] = gbase + total;
  __syncthreads();

  for (int i = t; i < total; i += 256) {
    unsigned int p = pk[i];
    int dl = p >> 19;
    int ofs = atomicAdd(&cnt[dl], 1);
    pairs[gbase + ofs] = p & 0x7FFFFu;   // now holds src only
  }
}

// ---------------------------------------------------------------------------
// K2 v8 (fused aggregate+conv+pool).  Gather = v5 body verbatim (best known,
// 80.7us, bit-identical summation tree; no degree sort -- R6 showed the
// gather is memory-system-throughput-bound, sort only added overhead) with
// two latency cuts that keep request count identical:
//  (a) row pointers rp_s[129] in LDS (contiguous incl. sentinel, v7-proven);
//  (b) edge srcs esrc[] staged in LDS (coalesced, v6-proven correct) so the
//      4-edge index read is an LDS broadcast instead of a global round-trip.
// MFMA phase unchanged (wave-per-column-slice, B operand in VGPRs from Wt).
// ---------------------------------------------------------------------------
#define CB_NODES 128
#define ESTG 1024
__global__ __launch_bounds__(512, 6) void k_aggconv(const unsigned short* __restrict__ xb,
                                                    const int* __restrict__ S,
                                                    const unsigned int* __restrict__ bucket,
                                                    const int* __restrict__ node_batch,
                                                    const unsigned short* __restrict__ Wt,
                                                    const float* __restrict__ bconv,
                                                    float* __restrict__ g) {
  __shared__ unsigned short As[128 * 136];  // [m][0:64)=agg, [64:128)=x; later h[m][n]
  __shared__ int esrc[ESTG];
  __shared__ int nb_s[CB_NODES];
  __shared__ int rp_s[CB_NODES + 1];
  const int t = threadIdx.x;
  const int n0 = blockIdx.x * CB_NODES;
  const int sidx0 = n0 + (n0 >> 10);

  if (t < CB_NODES) nb_s[t] = node_batch[n0 + t];
  if (t < CB_NODES + 1) rp_s[t] = S[sidx0 + t];   // valid incl. sentinel at bin end

  // stage edge srcs for the whole block (contiguous, coalesced)
  const int eStart = S[sidx0];
  {
    int EB = S[sidx0 + CB_NODES] - eStart;
    if (EB > ESTG) EB = ESTG;                // 22-sigma guard
    for (int i = t; i < EB; i += 512) esrc[i] = bucket[eStart + i];
  }

  // stage x half of As.  1024 ushort8 slots, 2/thread.
#pragma unroll
  for (int it = 0; it < 2; ++it) {
    int i = it * 512 + t;
    int n = i >> 3;
    int c = i & 7;
    *(ushort8*)(As + n * 136 + 64 + c * 8) =
        *(const ushort8*)(xb + (size_t)(n0 + n) * FIN + c * 8);
  }
  __syncthreads();   // esrc, rp_s ready

  // phase 2: gather (v5 body).  4 lanes per node (32B each), 128 nodes/pass.
  {
    const int lane4 = t & 3;          // 16-elem slice within row
    const int grp = t >> 2;           // 0..127: node within block
    const int rp0 = rp_s[grp];
    const int rp1 = rp_s[grp + 1];
    int rp1c = rp1;
    if (rp1c > eStart + ESTG) rp1c = eStart + ESTG;  // never fires statistically
    const int co = lane4 << 4;        // element offset of this lane's 32B slice

    float a[16];
#pragma unroll
    for (int j = 0; j < 16; ++j) a[j] = 0.f;

    int e = rp0;
    for (; e + 3 < rp1c; e += 4) {
      int s0 = esrc[e - eStart], s1 = esrc[e + 1 - eStart];
      int s2 = esrc[e + 2 - eStart], s3 = esrc[e + 3 - eStart];
      const unsigned short* r0 = xb + (size_t)s0 * FIN + co;
      const unsigned short* r1 = xb + (size_t)s1 * FIN + co;
      const unsigned short* r2 = xb + (size_t)s2 * FIN + co;
      const unsigned short* r3 = xb + (size_t)s3 * FIN + co;
      ushort8 v0a = *(const ushort8*)(r0), v0b = *(const ushort8*)(r0 + 8);
      ushort8 v1a = *(const ushort8*)(r1), v1b = *(const ushort8*)(r1 + 8);
      ushort8 v2a = *(const ushort8*)(r2), v2b = *(const ushort8*)(r2 + 8);
      ushort8 v3a = *(const ushort8*)(r3), v3b = *(const ushort8*)(r3 + 8);
#pragma unroll
      for (int j = 0; j < 8; ++j) {
        a[j]     += (b2f(v0a[j]) + b2f(v1a[j])) + (b2f(v2a[j]) + b2f(v3a[j]));
        a[8 + j] += (b2f(v0b[j]) + b2f(v1b[j])) + (b2f(v2b[j]) + b2f(v3b[j]));
      }
    }
    for (; e < rp1c; ++e) {
      int s0 = esrc[e - eStart];
      const unsigned short* r0 = xb + (size_t)s0 * FIN + co;
      ushort8 v0a = *(const ushort8*)(r0), v0b = *(const ushort8*)(r0 + 8);
#pragma unroll
      for (int j = 0; j < 8; ++j) {
        a[j] += b2f(v0a[j]);
        a[8 + j] += b2f(v0b[j]);
      }
    }
    float rdeg = 1.f / fmaxf((float)(rp1 - rp0), 1.f);
    ushort8 r0, r1;
#pragma unroll
    for (int j = 0; j < 8; ++j) { r0[j] = f2b(a[j] * rdeg); r1[j] = f2b(a[8 + j] * rdeg); }
    *(ushort8*)(As + grp * 136 + co) = r0;
    *(ushort8*)(As + grp * 136 + co + 8) = r1;
  }

  // phase 3: MFMA.  wave w owns output cols w*16..w*16+15, all 128 rows.
  const int wave = t >> 6;
  const int lane = t & 63;
  const int l16 = lane & 15;
  const int quad = lane >> 4;

  bf16x8 bfrag[4];
#pragma unroll
  for (int ks = 0; ks < 4; ++ks)
    bfrag[ks] = *(const bf16x8*)(Wt + (size_t)(wave * 16 + l16) * HIDDEN + ks * 32 + quad * 8);
  float bv = bconv[wave * 16 + l16];

  floatx4 acc[8];
#pragma unroll
  for (int mt = 0; mt < 8; ++mt) acc[mt] = (floatx4){0.f, 0.f, 0.f, 0.f};

  __syncthreads();

#pragma unroll
  for (int mt = 0; mt < 8; ++mt) {
#pragma unroll
    for (int ks = 0; ks < 4; ++ks) {
      bf16x8 a = *(const bf16x8*)(As + (mt * 16 + l16) * 136 + ks * 32 + quad * 8);
      acc[mt] = __builtin_amdgcn_mfma_f32_16x16x32_bf16(a, bfrag[ks], acc[mt], 0, 0, 0);
    }
  }

  __syncthreads();   // all waves done reading As before h overwrites it

  // epilogue: bias+relu -> h bf16 into As
  {
    int col = wave * 16 + l16;
#pragma unroll
    for (int mt = 0; mt < 8; ++mt)
#pragma unroll
      for (int r = 0; r < 4; ++r) {
        int row = mt * 16 + quad * 4 + r;
        float hv = fmaxf(acc[mt][r] + bv, 0.f);
        As[row * 136 + col] = f2b(hv);
      }
  }
  __syncthreads();

  // segmented pool: 4 threads per col, 32 nodes each (sorted node_batch)
  {
    int j = t & 127;
    int q = t >> 7;
    int ns = q * 32, ne = ns + 32;
    float sum = 0.f;
    int cur = nb_s[ns];
    for (int n = ns; n < ne; ++n) {
      int b = nb_s[n];
      if (b != cur) {
        unsafeAtomicAdd(&g[(size_t)cur * HIDDEN + j], sum);
        sum = 0.f;
        cur = b;
      }
      sum += b2f(As[n * 136 + j]);
    }
    unsafeAtomicAdd(&g[(size_t)cur * HIDDEN + j], sum);
  }
}

// ---------------------------------------------------------------------------
// K3 v2: MLP head.  W1 staged in LDS once per block (64KB), 16 subgraphs per
// block (4 waves x 4) -> W1 L2 traffic 512MB -> 32MB.
// ---------------------------------------------------------------------------
#define HB_SG 16
__global__ __launch_bounds__(256) void k_head(const float* __restrict__ g,
                                              const float* __restrict__ W1,
                                              const float* __restrict__ b1,
                                              const float* __restrict__ W2,
                                              const float* __restrict__ b2,
                                              const float* __restrict__ wts,
                                              const int* __restrict__ sgb,
                                              float* __restrict__ egy,
                                              float* __restrict__ nrm) {
  __shared__ float W1s[HIDDEN * HIDDEN];  // 64KB
  const int t = threadIdx.x;
#pragma unroll
  for (int it = 0; it < 16; ++it) {
    int i = (it * 256 + t) * 4;
    *(float4*)(W1s + i) = *(const float4*)(W1 + i);
  }
  const int wv = t >> 6;
  const int lane = t & 63;
  const float b1a = b1[lane], b1b = b1[lane + 64];
  const float w2a = W2[lane], w2b = W2[lane + 64];
  __syncthreads();
#pragma unroll
  for (int q = 0; q < HB_SG / 4; ++q) {
    int s = blockIdx.x * HB_SG + q * 4 + wv;
    const float* grow = g + (size_t)s * HIDDEN;
    float acc0 = b1a, acc1 = b1b;
    for (int k = 0; k < HIDDEN; ++k) {
      float gk = grow[k];  // wave-uniform
      acc0 = fmaf(gk, W1s[k * HIDDEN + lane], acc0);
      acc1 = fmaf(gk, W1s[k * HIDDEN + 64 + lane], acc1);
    }
    float t0 = acc0 > 0.f ? acc0 : 0.01f * acc0;
    float t1 = acc1 > 0.f ? acc1 : 0.01f * acc1;
    float part = t0 * w2a + t1 * w2b;
#pragma unroll
    for (int off = 32; off > 0; off >>= 1) part += __shfl_down(part, off, 64);
    if (lane == 0) {
      float sval = part + b2[0];
      float w = wts[s];
      int grp = sgb[s];
      unsafeAtomicAdd(&egy[grp], sval * w);
      unsafeAtomicAdd(&nrm[grp], w);
    }
  }
}

__global__ void k_final(const float* __restrict__ egy,
                        const float* __restrict__ nrm,
                        float* __restrict__ out) {
  int t = threadIdx.x;
  out[t] = egy[t] / nrm[t];
}

// ---------------------------------------------------------------------------
extern "C" void kernel_launch(void* const* d_in, const int* in_sizes, int n_in,
                              void* d_out, int out_size, void* d_ws, size_t ws_size,
                              hipStream_t stream) {
  const float* x   = (const float*)d_in[0];
  const int*   ei  = (const int*)d_in[1];
  const int*   nb  = (const int*)d_in[2];
  const float* wts = (const float*)d_in[3];
  const int*   sgb = (const int*)d_in[4];
  const float* Wl  = (const float*)d_in[5];
  const float* Wr  = (const float*)d_in[6];
  const float* bcv = (const float*)d_in[7];
  const float* W1  = (const float*)d_in[8];
  const float* b1  = (const float*)d_in[9];
  const float* W2  = (const float*)d_in[10];
  const float* b2  = (const float*)d_in[11];
  float* out = (float*)d_out;

  // ws layout (4B units), zeroed region first:
  //   binCursor[512] | g[NS*128] | egy[64] | nrm[64]   <- memset 0
  //   S[512*1025] | pairs[512*4608] | xb[NN*64 bf16] | Wt[16384 bf16]
  int*   binCursor = (int*)d_ws;
  float* g         = (float*)(binCursor + NB);
  float* egy       = g + (size_t)NS * HIDDEN;
  float* nrm       = egy + NG;
  int*   S         = (int*)(nrm + NG);
  unsigned int* pairs = (unsigned int*)(S + NB * (BIN_NODES + 1));
  unsigned short* xb   = (unsigned short*)(pairs + (size_t)NB * CAP);
  unsigned short* Wt   = xb + (size_t)NN * FIN;

  size_t zero_bytes = ((size_t)NB + (size_t)NS * HIDDEN + 2 * NG) * 4;
  hipMemsetAsync(d_ws, 0, zero_bytes, stream);

  k_cast <<<16448, 256, 0, stream>>>(x, xb, Wl, Wr, Wt);
  k_bin1 <<<NE / 4096, 256, 0, stream>>>(ei, binCursor, pairs);
  k_bin2 <<<NB, 256, 0, stream>>>(binCursor, pairs, S);
  k_aggconv<<<NN / CB_NODES, 512, 0, stream>>>(xb, S, pairs, nb, Wt, bcv, g);
  k_head<<<NS / HB_SG, 256, 0, stream>>>(g, W1, b1, W2, b2, wts, sgb, egy, nrm);
  k_final<<<1, 64, 0, stream>>>(egy, nrm, out);
}